// Round 14
// baseline (554.218 us; speedup 1.0000x reference)
//
#include <hip/hip_runtime.h>

#define DI __device__ __forceinline__

typedef float f32x4 __attribute__((ext_vector_type(4)));
typedef float f4    __attribute__((ext_vector_type(4)));
typedef float f2    __attribute__((ext_vector_type(2)));
typedef _Float16 h8 __attribute__((ext_vector_type(8)));
typedef _Float16 h4 __attribute__((ext_vector_type(4)));

// sizes
#define SEQL 512
#define BATCH 256
#define INF 300
#define HID 256
#define N2 512   // 2*HID
#define KP 320   // INF padded to multiple of 64
#define RNN_BLOCKS 32
#define GEMM_BLOCKS 2048

// pre3 layout: element (t, j, b) at byte t*262144 + (j>>4)*8192 + b*32 + (j&15)*2

DI float ftanh(float x) {
    float e = __builtin_amdgcn_exp2f(x * 2.8853900817779268f);
    return fmaf(-2.0f, __builtin_amdgcn_rcpf(e + 1.0f), 1.0f);
}

DI h4 ald8(const void* p) {
    unsigned long long u = __hip_atomic_load((const unsigned long long*)p,
                                             __ATOMIC_RELAXED, __HIP_MEMORY_SCOPE_AGENT);
    union { unsigned long long u; h4 h; } c; c.u = u; return c.h;
}

// ---------------- prep: WcatT (xor-swizzled f16) + bcat + group-flag reset ----------------
__global__ void prep_kernel(const float* __restrict__ W1x, const float* __restrict__ W2x,
                            const float* __restrict__ b1, const float* __restrict__ b2,
                            _Float16* __restrict__ WTs, float* __restrict__ bcat,
                            unsigned* __restrict__ gflags)
{
    int idx = blockIdx.x * 256 + threadIdx.x;
    if (idx < N2 * KP) {
        int j = idx / KP, z = idx - j * KP;
        int k = z ^ ((j & 7) << 3);
        float v = 0.f;
        if (k < INF) v = (j < HID) ? W1x[k * HID + j] : W2x[k * HID + (j - HID)];
        WTs[j * KP + z] = (_Float16)v;
    }
    if (idx < N2) bcat[idx] = (idx < HID) ? b1[idx] : b2[idx - HID];
    if (idx < 64) gflags[idx] = 0u;   // 64 groups x 8 timesteps, target 32 each
}

// ---------------- fused body: [0,32) rnn consumers, [32,2080) gemm producers ----------------
DI void fused_body(char* smem,
    const float* __restrict__ x, const _Float16* __restrict__ WTs,
    const float* __restrict__ bcat,
    const float* __restrict__ W1h, const float* __restrict__ W2h,
    _Float16* __restrict__ pre3, float* __restrict__ hcat,
    unsigned* __restrict__ gflags)
{
    const int tid = threadIdx.x;
    const int w = tid >> 6, l = tid & 63;
    const int lj = l & 15, lg = l >> 4;

    if (blockIdx.x >= RNN_BLOCKS) {
        // ================= GEMM producer (R12-verified) =================
        _Float16* Ab = (_Float16*)smem;            // 16KB x tile, xor-swizzled rows
        _Float16* Bb = (_Float16*)(smem + 16384);  // 32KB W tile, xor-swizzled rows
        const int g = blockIdx.x - RNN_BLOCKS;     // [0,2048)
        const int k4i = g >> 2, r = g & 3;
        const int t = (k4i & 1) ? (511 - (k4i >> 1)) : (k4i >> 1);  // both-ends order
        const int bm = 2 * t + (r >> 1);
        const int jn = r & 1;
        const size_t m0 = (size_t)bm * 128;
        const int j0b = jn * 256;
        const int wj = (w >> 1) * 64, wm2 = (w & 1) * 64;

        f32x4 acc[4][4];
#pragma unroll
        for (int a = 0; a < 4; ++a)
#pragma unroll
            for (int b = 0; b < 4; ++b) acc[a][b] = f32x4{0.f, 0.f, 0.f, 0.f};

        char* AbC = (char*)Ab;
        char* BbC = (char*)Bb;

        for (int s = 0; s < 5; ++s) {
            const int k0 = s * 64;
#pragma unroll
            for (int q = 0; q < 4; ++q) {
                int idx = q * 512 + tid;
                int jr = idx >> 3, sl = idx & 7;
                const _Float16* src = WTs + (size_t)(j0b + jr) * KP + k0 + sl * 8;
                _Float16* dst = &Bb[(q * 512 + w * 64) * 8];
                __builtin_amdgcn_global_load_lds(
                    (const __attribute__((address_space(1))) void*)src,
                    (__attribute__((address_space(3))) void*)dst, 16, 0, 0);
            }
#pragma unroll
            for (int c = 0; c < 4; ++c) {
                int f = c * 512 + tid;
                int mr = f >> 4, kq = f & 15;
                f4 v;
                if (k0 + kq * 4 + 3 < INF)
                    v = *(const f4*)(x + (m0 + mr) * INF + k0 + kq * 4);
                else
                    v = f4{0.f, 0.f, 0.f, 0.f};
                unsigned bo = (unsigned)mr * 128 + (((unsigned)kq * 8) ^ ((mr & 7) << 4));
                *(h4*)(AbC + bo) = h4{(_Float16)v[0], (_Float16)v[1], (_Float16)v[2], (_Float16)v[3]};
            }
            __syncthreads();
#pragma unroll
            for (int kk = 0; kk < 2; ++kk) {
                h8 aw[4], bx[4];
#pragma unroll
                for (int jt = 0; jt < 4; ++jt) {
                    int jr = wj + jt * 16 + lj;
                    unsigned bo = (unsigned)jr * 128 + (((unsigned)(kk * 64 + lg * 16)) ^ ((jr & 7) << 4));
                    aw[jt] = *(const h8*)(BbC + bo);
                }
#pragma unroll
                for (int mt = 0; mt < 4; ++mt) {
                    int mr = wm2 + mt * 16 + lj;
                    unsigned bo = (unsigned)mr * 128 + (((unsigned)(kk * 64 + lg * 16)) ^ ((mr & 7) << 4));
                    bx[mt] = *(const h8*)(AbC + bo);
                }
#pragma unroll
                for (int jt = 0; jt < 4; ++jt)
#pragma unroll
                    for (int mt = 0; mt < 4; ++mt)
                        acc[jt][mt] = __builtin_amdgcn_mfma_f32_16x16x32_f16(aw[jt], bx[mt], acc[jt][mt], 0, 0, 0);
            }
            __syncthreads();
        }
        f4 bias4[4];
#pragma unroll
        for (int jt = 0; jt < 4; ++jt)
            bias4[jt] = *(const f4*)(bcat + j0b + wj + jt * 16 + lg * 4);
        char* prc = (char*)pre3;
#pragma unroll
        for (int jt = 0; jt < 4; ++jt) {
            int slab = (j0b + wj + jt * 16) >> 4;
#pragma unroll
            for (int mt = 0; mt < 4; ++mt) {
                int M = (int)m0 + wm2 + mt * 16;
                size_t byte = (size_t)(M >> 8) * 262144 + (size_t)slab * 8192
                            + (size_t)((M & 255) + lj) * 32 + (size_t)lg * 8;
                h4 o;
#pragma unroll
                for (int i = 0; i < 4; ++i)
                    o[i] = (_Float16)(acc[jt][mt][i] + bias4[jt][i]);
                *(h4*)(prc + byte) = o;
            }
        }
        __syncthreads();  // all stores issued & waves arrived
        if (tid == 0)
            __hip_atomic_fetch_add(&gflags[t >> 3], 1u, __ATOMIC_RELEASE, __HIP_MEMORY_SCOPE_AGENT);
        return;
    }

    // ================= RNN consumer (group-granular flag waits) =================
    __builtin_amdgcn_s_setprio(2);
    char* hbc = smem;  // [2][8192]
    const int dir = blockIdx.x & 1;
    const int b0 = (int)(blockIdx.x >> 1) * 16;
    const float* Wh = dir ? W2h : W1h;
    const int j0 = w * 32;
    const int dirOff = dir ? HID : 0;

    h8 afrag[2][8];
#pragma unroll
    for (int jt = 0; jt < 2; ++jt) {
        int jc = j0 + jt * 16 + lj;
#pragma unroll
        for (int kk = 0; kk < 8; ++kk) {
            h8 tr;
#pragma unroll
            for (int i = 0; i < 8; ++i) tr[i] = (_Float16)Wh[(kk * 32 + lg * 8 + i) * HID + jc];
            afrag[jt][kk] = tr;
        }
    }

    const unsigned rb = (unsigned)l * 16;
    const unsigned wb0 = (unsigned)w * 1024 + (unsigned)(lg >> 1) * 256
                       + (unsigned)lj * 16 + (unsigned)(lg & 1) * 8;

    ((h8*)hbc)[tid] = h8{0, 0, 0, 0, 0, 0, 0, 0};
    __syncthreads();

    // group wait: uniform address, all lanes spin identically (no barrier needed)
#define WAITG(G)                                                                      \
    while (__hip_atomic_load(&gflags[(G)], __ATOMIC_ACQUIRE, __HIP_MEMORY_SCOPE_AGENT) < 32u) \
        __builtin_amdgcn_s_sleep(8)

    const int G0 = dir ? 63 : 0;
    const int gstep = dir ? -1 : 1;
    WAITG(G0);
    WAITG(G0 + gstep);

    const long long sb = dir ? -262144LL : 262144LL;
    const char* pp = (const char*)pre3 + (long long)(dir ? (SEQL - 1) : 0) * 262144
                   + (long long)dir * 131072
                   + (long long)w * 16384 + (long long)(b0 + lj) * 32 + lg * 8;
    h4 pA[2], pB[2];
    pA[0] = ald8(pp); pA[1] = ald8(pp + 8192); pp += sb;
    pB[0] = ald8(pp); pB[1] = ald8(pp + 8192); pp += sb;

#define RNN_STEP(RB, WB, P, DO_PF)                                                    \
    do {                                                                              \
        h8 bf[8];                                                                     \
        _Pragma("unroll")                                                             \
        for (int kk = 0; kk < 8; ++kk)                                                \
            bf[kk] = *(const h8*)(hbc + (RB) + kk * 1024 + rb);                       \
        f32x4 acc0, acc1;                                                             \
        _Pragma("unroll")                                                             \
        for (int i = 0; i < 4; ++i) { acc0[i] = (float)P[0][i]; acc1[i] = (float)P[1][i]; } \
        if (DO_PF) {                                                                  \
            P[0] = ald8(pp);                                                          \
            P[1] = ald8(pp + 8192);                                                   \
            pp += sb;                                                                 \
        }                                                                             \
        _Pragma("unroll")                                                             \
        for (int kk = 0; kk < 8; ++kk)                                                \
            acc0 = __builtin_amdgcn_mfma_f32_16x16x32_f16(afrag[0][kk], bf[kk], acc0, 0, 0, 0); \
        h4 o0;                                                                        \
        _Pragma("unroll")                                                             \
        for (int i = 0; i < 4; ++i) o0[i] = (_Float16)ftanh(acc0[i]);                 \
        *(h4*)(hbc + (WB) + wb0) = o0;                                                \
        _Pragma("unroll")                                                             \
        for (int kk = 0; kk < 8; ++kk)                                                \
            acc1 = __builtin_amdgcn_mfma_f32_16x16x32_f16(afrag[1][kk], bf[kk], acc1, 0, 0, 0); \
        h4 o1;                                                                        \
        _Pragma("unroll")                                                             \
        for (int i = 0; i < 4; ++i) o1[i] = (_Float16)ftanh(acc1[i]);                 \
        *(h4*)(hbc + (WB) + wb0 + 512) = o1;                                          \
        __builtin_amdgcn_sched_barrier(0);                                            \
        asm volatile("s_waitcnt lgkmcnt(0)" ::: "memory");                            \
        __builtin_amdgcn_s_barrier();                                                 \
        __builtin_amdgcn_sched_barrier(0);                                            \
    } while (0)

    // 63 groups x 8 steps (4 buf0/buf1 pairs each); wait one group ahead
    for (int i = 0; i < 63; ++i) {
        if (i >= 1) { WAITG(G0 + (i + 1) * gstep); }
        for (int p = 0; p < 4; ++p) {
            RNN_STEP(0, 8192, pA, 1);
            RNN_STEP(8192, 0, pB, 1);
        }
    }
    // final group: steps 504..509 (3 pairs), 510, 511
    for (int p = 0; p < 3; ++p) {
        RNN_STEP(0, 8192, pA, 1);
        RNN_STEP(8192, 0, pB, 1);
    }
    RNN_STEP(0, 8192, pA, 0);
    {
        f32x4 acc0, acc1;
#pragma unroll
        for (int i = 0; i < 4; ++i) { acc0[i] = (float)pB[0][i]; acc1[i] = (float)pB[1][i]; }
        h8 bf[8];
#pragma unroll
        for (int kk = 0; kk < 8; ++kk)
            bf[kk] = *(const h8*)(hbc + 8192 + kk * 1024 + rb);
#pragma unroll
        for (int kk = 0; kk < 8; ++kk) {
            acc0 = __builtin_amdgcn_mfma_f32_16x16x32_f16(afrag[0][kk], bf[kk], acc0, 0, 0, 0);
            acc1 = __builtin_amdgcn_mfma_f32_16x16x32_f16(afrag[1][kk], bf[kk], acc1, 0, 0, 0);
        }
        f4 v0, v1;
#pragma unroll
        for (int i = 0; i < 4; ++i) { v0[i] = ftanh(acc0[i]); v1[i] = ftanh(acc1[i]); }
        float* hc = hcat + (size_t)(b0 + lj) * N2 + dirOff + j0 + lg * 4;
        *(f4*)hc = v0;
        *(f4*)(hc + 16) = v1;
    }
#undef RNN_STEP
#undef WAITG
}

// dynamic-LDS variant: 80KB/block -> 1 block/CU (rnn blocks get exclusive CUs)
__global__ __launch_bounds__(512, 1) void fused_kernel_dyn(
    const float* __restrict__ x, const _Float16* __restrict__ WTs,
    const float* __restrict__ bcat,
    const float* __restrict__ W1h, const float* __restrict__ W2h,
    _Float16* __restrict__ pre3, float* __restrict__ hcat,
    unsigned* __restrict__ gflags)
{
    extern __shared__ char smem[];
    fused_body(smem, x, WTs, bcat, W1h, W2h, pre3, hcat, gflags);
}

// static fallback if the dynamic-LDS attribute is unavailable
__global__ __launch_bounds__(512, 2) void fused_kernel_sta(
    const float* __restrict__ x, const _Float16* __restrict__ WTs,
    const float* __restrict__ bcat,
    const float* __restrict__ W1h, const float* __restrict__ W2h,
    _Float16* __restrict__ pre3, float* __restrict__ hcat,
    unsigned* __restrict__ gflags)
{
    __shared__ char smem[49152];
    fused_body(smem, x, WTs, bcat, W1h, W2h, pre3, hcat, gflags);
}

// ---------------- head: 64 blocks x 4 batch-rows (R6-verified, cleaned) ----------------
__global__ __launch_bounds__(256) void head_mlp(
    const float* __restrict__ hcat,
    const float* __restrict__ fc1w, const float* __restrict__ fc1b,
    const float* __restrict__ fc2w, const float* __restrict__ fc2b,
    const float* __restrict__ fsw, const float* __restrict__ fsb,
    float* __restrict__ out)
{
    __shared__ float hs[4 * 512];
    __shared__ float y1[4 * 512];
    __shared__ float y2[4 * 256];
    const int tid = threadIdx.x;
    const int b0 = blockIdx.x * 4;
    const int r = tid >> 6;
    const int lane = tid & 63;

#pragma unroll
    for (int c = 0; c < 2; ++c)
        ((f4*)hs)[c * 256 + tid] = ((const f4*)(hcat + (size_t)b0 * N2))[c * 256 + tid];
    __syncthreads();

    {
        const int j0 = lane * 8;
        f4 a0 = *(const f4*)(fc1b + j0);
        f4 a1 = *(const f4*)(fc1b + j0 + 4);
        for (int k = 0; k < 512; ++k) {
            float h = hs[r * 512 + k];
            f4 w0 = *(const f4*)(fc1w + (size_t)k * 512 + j0);
            f4 w1 = *(const f4*)(fc1w + (size_t)k * 512 + j0 + 4);
#pragma unroll
            for (int i = 0; i < 4; ++i) { a0[i] = fmaf(h, w0[i], a0[i]); a1[i] = fmaf(h, w1[i], a1[i]); }
        }
#pragma unroll
        for (int i = 0; i < 4; ++i) {
            y1[r * 512 + j0 + i]     = fmaxf(a0[i], 0.f);
            y1[r * 512 + j0 + 4 + i] = fmaxf(a1[i], 0.f);
        }
    }
    __syncthreads();

    {
        const int j2 = lane * 4;
        f4 a = *(const f4*)(fc2b + j2);
        for (int k = 0; k < 512; ++k) {
            float yv = y1[r * 512 + k];
            f4 w = *(const f4*)(fc2w + (size_t)k * 256 + j2);
#pragma unroll
            for (int i = 0; i < 4; ++i) a[i] = fmaf(yv, w[i], a[i]);
        }
#pragma unroll
        for (int i = 0; i < 4; ++i) y2[r * 256 + j2 + i] = fmaxf(a[i], 0.f);
    }
    __syncthreads();

    {
        float p = 0.f;
#pragma unroll
        for (int u = 0; u < 4; ++u)
            p = fmaf(y2[r * 256 + lane + u * 64], fsw[lane + u * 64], p);
#pragma unroll
        for (int off = 32; off > 0; off >>= 1) p += __shfl_down(p, off);
        if (lane == 0) out[b0 + r] = ftanh(p + fsb[0]);
    }
}

extern "C" void kernel_launch(void* const* d_in, const int* in_sizes, int n_in,
                              void* d_out, int out_size, void* d_ws, size_t ws_size,
                              hipStream_t stream)
{
    const float* x    = (const float*)d_in[0];
    const float* W1x  = (const float*)d_in[1];
    const float* W1h  = (const float*)d_in[2];
    const float* b1   = (const float*)d_in[3];
    const float* W2x  = (const float*)d_in[4];
    const float* W2h  = (const float*)d_in[5];
    const float* b2   = (const float*)d_in[6];
    const float* fc1w = (const float*)d_in[7];
    const float* fc1b = (const float*)d_in[8];
    const float* fc2w = (const float*)d_in[9];
    const float* fc2b = (const float*)d_in[10];
    const float* fsw  = (const float*)d_in[11];
    const float* fsb  = (const float*)d_in[12];

    char* ws = (char*)d_ws;
    size_t off = 0;
    _Float16* WTs    = (_Float16*)(ws + off); off += (size_t)N2 * KP * sizeof(_Float16);
    float* bcat      = (float*)(ws + off);    off += (size_t)N2 * sizeof(float);
    float* hcat      = (float*)(ws + off);    off += (size_t)BATCH * N2 * sizeof(float);
    unsigned* gflags = (unsigned*)(ws + off); off += 4096;  // 64 used
    _Float16* pre3   = (_Float16*)(ws + off); off += (size_t)SEQL * BATCH * N2 * sizeof(_Float16);
    if (off > ws_size) return;

    prep_kernel<<<(N2 * KP + 255) / 256, 256, 0, stream>>>(W1x, W2x, b1, b2, WTs, bcat, gflags);

    static hipError_t attr_err = hipFuncSetAttribute(
        (const void*)fused_kernel_dyn, hipFuncAttributeMaxDynamicSharedMemorySize, 81920);
    if (attr_err == hipSuccess) {
        fused_kernel_dyn<<<RNN_BLOCKS + GEMM_BLOCKS, 512, 81920, stream>>>(
            x, WTs, bcat, W1h, W2h, pre3, hcat, gflags);
    } else {
        fused_kernel_sta<<<RNN_BLOCKS + GEMM_BLOCKS, 512, 0, stream>>>(
            x, WTs, bcat, W1h, W2h, pre3, hcat, gflags);
    }
    head_mlp<<<64, 256, 0, stream>>>(hcat, fc1w, fc1b, fc2w, fc2b, fsw, fsb, (float*)d_out);
}

// Round 15
// 524.006 us; speedup vs baseline: 1.0577x; 1.0577x over previous
//
#include <hip/hip_runtime.h>

#define DI __device__ __forceinline__

typedef float f32x4 __attribute__((ext_vector_type(4)));
typedef float f4    __attribute__((ext_vector_type(4)));
typedef _Float16 h8 __attribute__((ext_vector_type(8)));
typedef _Float16 h4 __attribute__((ext_vector_type(4)));

// sizes
#define SEQL 512
#define BATCH 256
#define INF 300
#define HID 256
#define N2 512   // 2*HID
#define KP 320   // INF padded to multiple of 64
#define RNN_BLOCKS 32
#define GEMM_BLOCKS 2048

// pre3 layout: element (t, j, b) at byte t*262144 + (j>>4)*8192 + b*32 + (j&15)*2

DI float ftanh(float x) {
    float e = __builtin_amdgcn_exp2f(x * 2.8853900817779268f);
    return fmaf(-2.0f, __builtin_amdgcn_rcpf(e + 1.0f), 1.0f);
}

DI h4 ald8(const void* p) {
    unsigned long long u = __hip_atomic_load((const unsigned long long*)p,
                                             __ATOMIC_RELAXED, __HIP_MEMORY_SCOPE_AGENT);
    union { unsigned long long u; h4 h; } c; c.u = u; return c.h;
}

// ---------------- prep: WcatT (xor-swizzled f16) + bcat + group-flag reset ----------------
__global__ void prep_kernel(const float* __restrict__ W1x, const float* __restrict__ W2x,
                            const float* __restrict__ b1, const float* __restrict__ b2,
                            _Float16* __restrict__ WTs, float* __restrict__ bcat,
                            unsigned* __restrict__ gflags)
{
    int idx = blockIdx.x * 256 + threadIdx.x;
    if (idx < N2 * KP) {
        int j = idx / KP, z = idx - j * KP;
        int k = z ^ ((j & 7) << 3);
        float v = 0.f;
        if (k < INF) v = (j < HID) ? W1x[k * HID + j] : W2x[k * HID + (j - HID)];
        WTs[j * KP + z] = (_Float16)v;
    }
    if (idx < N2) bcat[idx] = (idx < HID) ? b1[idx] : b2[idx - HID];
    if (idx < 64) gflags[idx] = 0u;   // 64 groups x 8 timesteps, target 32 each
}

// ---------------- fused: [0,32) rnn consumers, [32,2080) gemm producers ----------------
// Static 96KB LDS => 1 block/CU => rnn blocks own their CUs exclusively.
__global__ __launch_bounds__(512, 1) void fused_kernel(
    const float* __restrict__ x, const _Float16* __restrict__ WTs,
    const float* __restrict__ bcat,
    const float* __restrict__ W1h, const float* __restrict__ W2h,
    _Float16* __restrict__ pre3, float* __restrict__ hcat,
    unsigned* __restrict__ gflags)
{
    __shared__ char smem[98304];
    const int tid = threadIdx.x;
    const int w = tid >> 6, l = tid & 63;
    const int lj = l & 15, lg = l >> 4;

    if (blockIdx.x >= RNN_BLOCKS) {
        // ================= GEMM producer (R13-verified dbuf body) =================
        char* A0 = smem;                 // 16KB
        char* A1 = smem + 16384;         // 16KB
        char* B0 = smem + 32768;         // 32KB
        char* B1 = smem + 65536;         // 32KB
        const int g = blockIdx.x - RNN_BLOCKS;     // [0,2048)
        const int k4i = g >> 2, r = g & 3;
        const int t = (k4i & 1) ? (511 - (k4i >> 1)) : (k4i >> 1);  // both-ends order
        const int bm = 2 * t + (r >> 1);
        const int jn = r & 1;
        const size_t m0 = (size_t)bm * 128;
        const int j0b = jn * 256;
        const int wj = (w >> 1) * 64, wm2 = (w & 1) * 64;

        f32x4 acc[4][4];
#pragma unroll
        for (int a = 0; a < 4; ++a)
#pragma unroll
            for (int b = 0; b < 4; ++b) acc[a][b] = f32x4{0.f, 0.f, 0.f, 0.f};

        char* Acur = A0; char* Anxt = A1;
        char* Bcur = B0; char* Bnxt = B1;

#define STAGE_W(K0, BDST)                                                             \
    do {                                                                              \
        _Pragma("unroll")                                                             \
        for (int q = 0; q < 4; ++q) {                                                 \
            int idx = q * 512 + tid;                                                  \
            int jr = idx >> 3, sl = idx & 7;                                          \
            const _Float16* src = WTs + (size_t)(j0b + jr) * KP + (K0) + sl * 8;      \
            _Float16* dst = (_Float16*)(BDST) + (size_t)(q * 512 + w * 64) * 8;       \
            __builtin_amdgcn_global_load_lds(                                         \
                (const __attribute__((address_space(1))) void*)src,                   \
                (__attribute__((address_space(3))) void*)dst, 16, 0, 0);              \
        }                                                                             \
    } while (0)

#define LOAD_X(K0, XR)                                                                \
    do {                                                                              \
        _Pragma("unroll")                                                             \
        for (int c = 0; c < 4; ++c) {                                                 \
            int f = c * 512 + tid;                                                    \
            int mr = f >> 4, k4 = f & 15;                                             \
            if ((K0) + k4 * 4 + 3 < INF)                                              \
                XR[c] = *(const f4*)(x + (m0 + mr) * INF + (K0) + k4 * 4);            \
            else                                                                      \
                XR[c] = f4{0.f, 0.f, 0.f, 0.f};                                       \
        }                                                                             \
    } while (0)

#define WRITE_X(XR, ADST)                                                             \
    do {                                                                              \
        _Pragma("unroll")                                                             \
        for (int c = 0; c < 4; ++c) {                                                 \
            int f = c * 512 + tid;                                                    \
            int mr = f >> 4, k4 = f & 15;                                             \
            unsigned bo = (unsigned)mr * 128 + (((unsigned)k4 * 8) ^ ((mr & 7) << 4)); \
            *(h4*)((ADST) + bo) = h4{(_Float16)XR[c][0], (_Float16)XR[c][1],          \
                                     (_Float16)XR[c][2], (_Float16)XR[c][3]};         \
        }                                                                             \
    } while (0)

#define GBARRIER()                                                                    \
    do {                                                                              \
        __builtin_amdgcn_sched_barrier(0);                                            \
        asm volatile("s_waitcnt vmcnt(0) lgkmcnt(0)" ::: "memory");                   \
        __builtin_amdgcn_s_barrier();                                                 \
        __builtin_amdgcn_sched_barrier(0);                                            \
    } while (0)

        {
            f4 xr[4];
            STAGE_W(0, Bcur);
            LOAD_X(0, xr);
            asm volatile("s_waitcnt vmcnt(0)" ::: "memory");
            WRITE_X(xr, Acur);
            GBARRIER();
        }
        for (int s = 0; s < 5; ++s) {
            f4 xr[4];
            if (s < 4) {
                const int k0n = (s + 1) * 64;
                STAGE_W(k0n, Bnxt);
                LOAD_X(k0n, xr);
            }
#pragma unroll
            for (int kk = 0; kk < 2; ++kk) {
                h8 aw[4], bx[4];
#pragma unroll
                for (int jt = 0; jt < 4; ++jt) {
                    int jr = wj + jt * 16 + lj;
                    unsigned bo = (unsigned)jr * 128 + (((unsigned)(kk * 64 + lg * 16)) ^ ((jr & 7) << 4));
                    aw[jt] = *(const h8*)(Bcur + bo);
                }
#pragma unroll
                for (int mt = 0; mt < 4; ++mt) {
                    int mr = wm2 + mt * 16 + lj;
                    unsigned bo = (unsigned)mr * 128 + (((unsigned)(kk * 64 + lg * 16)) ^ ((mr & 7) << 4));
                    bx[mt] = *(const h8*)(Acur + bo);
                }
#pragma unroll
                for (int jt = 0; jt < 4; ++jt)
#pragma unroll
                    for (int mt = 0; mt < 4; ++mt)
                        acc[jt][mt] = __builtin_amdgcn_mfma_f32_16x16x32_f16(aw[jt], bx[mt], acc[jt][mt], 0, 0, 0);
            }
            if (s < 4) {
                asm volatile("s_waitcnt vmcnt(0)" ::: "memory");
                WRITE_X(xr, Anxt);
            }
            GBARRIER();
            char* t0 = Acur; Acur = Anxt; Anxt = t0;
            char* t1 = Bcur; Bcur = Bnxt; Bnxt = t1;
        }
#undef STAGE_W
#undef LOAD_X
#undef WRITE_X
#undef GBARRIER
        f4 bias4[4];
#pragma unroll
        for (int jt = 0; jt < 4; ++jt)
            bias4[jt] = *(const f4*)(bcat + j0b + wj + jt * 16 + lg * 4);
        char* prc = (char*)pre3;
#pragma unroll
        for (int jt = 0; jt < 4; ++jt) {
            int slab = (j0b + wj + jt * 16) >> 4;
#pragma unroll
            for (int mt = 0; mt < 4; ++mt) {
                int M = (int)m0 + wm2 + mt * 16;
                size_t byte = (size_t)(M >> 8) * 262144 + (size_t)slab * 8192
                            + (size_t)((M & 255) + lj) * 32 + (size_t)lg * 8;
                h4 o;
#pragma unroll
                for (int i = 0; i < 4; ++i)
                    o[i] = (_Float16)(acc[jt][mt][i] + bias4[jt][i]);
                *(h4*)(prc + byte) = o;
            }
        }
        __syncthreads();  // all stores issued & waves arrived
        if (tid == 0)
            __hip_atomic_fetch_add(&gflags[t >> 3], 1u, __ATOMIC_RELEASE, __HIP_MEMORY_SCOPE_AGENT);
        return;
    }

    // ================= RNN consumer (4-deep prefetch ring) =================
    __builtin_amdgcn_s_setprio(2);
    char* hbc = smem;  // [2][8192]
    const int dir = blockIdx.x & 1;
    const int b0 = (int)(blockIdx.x >> 1) * 16;
    const float* Wh = dir ? W2h : W1h;
    const int j0 = w * 32;
    const int dirOff = dir ? HID : 0;

    h8 afrag[2][8];
#pragma unroll
    for (int jt = 0; jt < 2; ++jt) {
        int jc = j0 + jt * 16 + lj;
#pragma unroll
        for (int kk = 0; kk < 8; ++kk) {
            h8 tr;
#pragma unroll
            for (int i = 0; i < 8; ++i) tr[i] = (_Float16)Wh[(kk * 32 + lg * 8 + i) * HID + jc];
            afrag[jt][kk] = tr;
        }
    }

    const unsigned rb = (unsigned)l * 16;
    const unsigned wb0 = (unsigned)w * 1024 + (unsigned)(lg >> 1) * 256
                       + (unsigned)lj * 16 + (unsigned)(lg & 1) * 8;

    ((h8*)hbc)[tid] = h8{0, 0, 0, 0, 0, 0, 0, 0};
    __syncthreads();

#define WAITG(G)                                                                      \
    while (__hip_atomic_load(&gflags[(G)], __ATOMIC_ACQUIRE, __HIP_MEMORY_SCOPE_AGENT) < 32u) \
        __builtin_amdgcn_s_sleep(8)

    const int G0 = dir ? 63 : 0;
    const int gstep = dir ? -1 : 1;
    WAITG(G0);
    WAITG(G0 + gstep);

    const long long sb = dir ? -262144LL : 262144LL;
    const char* pp = (const char*)pre3 + (long long)(dir ? (SEQL - 1) : 0) * 262144
                   + (long long)dir * 131072
                   + (long long)w * 16384 + (long long)(b0 + lj) * 32 + lg * 8;
    // prologue: 4-deep ring (8 loads in flight)
    h4 P0[2], P1[2], P2[2], P3[2];
    P0[0] = ald8(pp); P0[1] = ald8(pp + 8192); pp += sb;
    P1[0] = ald8(pp); P1[1] = ald8(pp + 8192); pp += sb;
    P2[0] = ald8(pp); P2[1] = ald8(pp + 8192); pp += sb;
    P3[0] = ald8(pp); P3[1] = ald8(pp + 8192); pp += sb;

#define RNN_STEP(RB, WB, P, DO_PF)                                                    \
    do {                                                                              \
        h8 bf[8];                                                                     \
        _Pragma("unroll")                                                             \
        for (int kk = 0; kk < 8; ++kk)                                                \
            bf[kk] = *(const h8*)(hbc + (RB) + kk * 1024 + rb);                       \
        f32x4 acc0, acc1;                                                             \
        _Pragma("unroll")                                                             \
        for (int i = 0; i < 4; ++i) { acc0[i] = (float)P[0][i]; acc1[i] = (float)P[1][i]; } \
        if (DO_PF) {                                                                  \
            P[0] = ald8(pp);                                                          \
            P[1] = ald8(pp + 8192);                                                   \
            pp += sb;                                                                 \
        }                                                                             \
        _Pragma("unroll")                                                             \
        for (int kk = 0; kk < 8; ++kk)                                                \
            acc0 = __builtin_amdgcn_mfma_f32_16x16x32_f16(afrag[0][kk], bf[kk], acc0, 0, 0, 0); \
        h4 o0;                                                                        \
        _Pragma("unroll")                                                             \
        for (int i = 0; i < 4; ++i) o0[i] = (_Float16)ftanh(acc0[i]);                 \
        *(h4*)(hbc + (WB) + wb0) = o0;                                                \
        _Pragma("unroll")                                                             \
        for (int kk = 0; kk < 8; ++kk)                                                \
            acc1 = __builtin_amdgcn_mfma_f32_16x16x32_f16(afrag[1][kk], bf[kk], acc1, 0, 0, 0); \
        h4 o1;                                                                        \
        _Pragma("unroll")                                                             \
        for (int i = 0; i < 4; ++i) o1[i] = (_Float16)ftanh(acc1[i]);                 \
        *(h4*)(hbc + (WB) + wb0 + 512) = o1;                                          \
        __builtin_amdgcn_sched_barrier(0);                                            \
        asm volatile("s_waitcnt lgkmcnt(0)" ::: "memory");                            \
        __builtin_amdgcn_s_barrier();                                                 \
        __builtin_amdgcn_sched_barrier(0);                                            \
    } while (0)

    // 126 quads = steps 0..503. Prefetch during quad q reaches step 4q+7, whose
    // group ((4q+7)>>3 = (q+1)>>1) is waited before the quad starts.
    for (int q = 0; q < 126; ++q) {
        if (q & 1) { WAITG(G0 + gstep * ((q + 1) >> 1)); }
        RNN_STEP(0, 8192, P0, 1);
        RNN_STEP(8192, 0, P1, 1);
        RNN_STEP(0, 8192, P2, 1);
        RNN_STEP(8192, 0, P3, 1);
    }
    // tail: group 63, steps 504..511
    WAITG(G0 + gstep * 63);
    RNN_STEP(0, 8192, P0, 1);   // 504 (prefetch 508)
    RNN_STEP(8192, 0, P1, 1);   // 505 (509)
    RNN_STEP(0, 8192, P2, 1);   // 506 (510)
    RNN_STEP(8192, 0, P3, 1);   // 507 (511)
    RNN_STEP(0, 8192, P0, 0);   // 508
    RNN_STEP(8192, 0, P1, 0);   // 509
    RNN_STEP(0, 8192, P2, 0);   // 510
    {
        // step 511: read buf1, write hcat
        f32x4 acc0, acc1;
#pragma unroll
        for (int i = 0; i < 4; ++i) { acc0[i] = (float)P3[0][i]; acc1[i] = (float)P3[1][i]; }
        h8 bf[8];
#pragma unroll
        for (int kk = 0; kk < 8; ++kk)
            bf[kk] = *(const h8*)(hbc + 8192 + kk * 1024 + rb);
#pragma unroll
        for (int kk = 0; kk < 8; ++kk) {
            acc0 = __builtin_amdgcn_mfma_f32_16x16x32_f16(afrag[0][kk], bf[kk], acc0, 0, 0, 0);
            acc1 = __builtin_amdgcn_mfma_f32_16x16x32_f16(afrag[1][kk], bf[kk], acc1, 0, 0, 0);
        }
        f4 v0, v1;
#pragma unroll
        for (int i = 0; i < 4; ++i) { v0[i] = ftanh(acc0[i]); v1[i] = ftanh(acc1[i]); }
        float* hc = hcat + (size_t)(b0 + lj) * N2 + dirOff + j0 + lg * 4;
        *(f4*)hc = v0;
        *(f4*)(hc + 16) = v1;
    }
#undef RNN_STEP
#undef WAITG
}

// ---------------- head: 64 blocks x 4 batch-rows (R6-verified) ----------------
__global__ __launch_bounds__(256) void head_mlp(
    const float* __restrict__ hcat,
    const float* __restrict__ fc1w, const float* __restrict__ fc1b,
    const float* __restrict__ fc2w, const float* __restrict__ fc2b,
    const float* __restrict__ fsw, const float* __restrict__ fsb,
    float* __restrict__ out)
{
    __shared__ float hs[4 * 512];
    __shared__ float y1[4 * 512];
    __shared__ float y2[4 * 256];
    const int tid = threadIdx.x;
    const int b0 = blockIdx.x * 4;
    const int r = tid >> 6;
    const int lane = tid & 63;

#pragma unroll
    for (int c = 0; c < 2; ++c)
        ((f4*)hs)[c * 256 + tid] = ((const f4*)(hcat + (size_t)b0 * N2))[c * 256 + tid];
    __syncthreads();

    {
        const int j0 = lane * 8;
        f4 a0 = *(const f4*)(fc1b + j0);
        f4 a1 = *(const f4*)(fc1b + j0 + 4);
        for (int k = 0; k < 512; ++k) {
            float h = hs[r * 512 + k];
            f4 w0 = *(const f4*)(fc1w + (size_t)k * 512 + j0);
            f4 w1 = *(const f4*)(fc1w + (size_t)k * 512 + j0 + 4);
#pragma unroll
            for (int i = 0; i < 4; ++i) { a0[i] = fmaf(h, w0[i], a0[i]); a1[i] = fmaf(h, w1[i], a1[i]); }
        }
#pragma unroll
        for (int i = 0; i < 4; ++i) {
            y1[r * 512 + j0 + i]     = fmaxf(a0[i], 0.f);
            y1[r * 512 + j0 + 4 + i] = fmaxf(a1[i], 0.f);
        }
    }
    __syncthreads();

    {
        const int j2 = lane * 4;
        f4 a = *(const f4*)(fc2b + j2);
        for (int k = 0; k < 512; ++k) {
            float yv = y1[r * 512 + k];
            f4 w = *(const f4*)(fc2w + (size_t)k * 256 + j2);
#pragma unroll
            for (int i = 0; i < 4; ++i) a[i] = fmaf(yv, w[i], a[i]);
        }
#pragma unroll
        for (int i = 0; i < 4; ++i) y2[r * 256 + j2 + i] = fmaxf(a[i], 0.f);
    }
    __syncthreads();

    {
        float p = 0.f;
#pragma unroll
        for (int u = 0; u < 4; ++u)
            p = fmaf(y2[r * 256 + lane + u * 64], fsw[lane + u * 64], p);
#pragma unroll
        for (int off = 32; off > 0; off >>= 1) p += __shfl_down(p, off);
        if (lane == 0) out[b0 + r] = ftanh(p + fsb[0]);
    }
}

extern "C" void kernel_launch(void* const* d_in, const int* in_sizes, int n_in,
                              void* d_out, int out_size, void* d_ws, size_t ws_size,
                              hipStream_t stream)
{
    const float* x    = (const float*)d_in[0];
    const float* W1x  = (const float*)d_in[1];
    const float* W1h  = (const float*)d_in[2];
    const float* b1   = (const float*)d_in[3];
    const float* W2x  = (const float*)d_in[4];
    const float* W2h  = (const float*)d_in[5];
    const float* b2   = (const float*)d_in[6];
    const float* fc1w = (const float*)d_in[7];
    const float* fc1b = (const float*)d_in[8];
    const float* fc2w = (const float*)d_in[9];
    const float* fc2b = (const float*)d_in[10];
    const float* fsw  = (const float*)d_in[11];
    const float* fsb  = (const float*)d_in[12];

    char* ws = (char*)d_ws;
    size_t off = 0;
    _Float16* WTs    = (_Float16*)(ws + off); off += (size_t)N2 * KP * sizeof(_Float16);
    float* bcat      = (float*)(ws + off);    off += (size_t)N2 * sizeof(float);
    float* hcat      = (float*)(ws + off);    off += (size_t)BATCH * N2 * sizeof(float);
    unsigned* gflags = (unsigned*)(ws + off); off += 4096;  // 64 used
    _Float16* pre3   = (_Float16*)(ws + off); off += (size_t)SEQL * BATCH * N2 * sizeof(_Float16);
    if (off > ws_size) return;

    prep_kernel<<<(N2 * KP + 255) / 256, 256, 0, stream>>>(W1x, W2x, b1, b2, WTs, bcat, gflags);
    fused_kernel<<<RNN_BLOCKS + GEMM_BLOCKS, 512, 0, stream>>>(
        x, WTs, bcat, W1h, W2h, pre3, hcat, gflags);
    head_mlp<<<64, 256, 0, stream>>>(hcat, fc1w, fc1b, fc2w, fc2b, fsw, fsb, (float*)d_out);
}

// Round 16
// 470.440 us; speedup vs baseline: 1.1781x; 1.1139x over previous
//
#include <hip/hip_runtime.h>

#define DI __device__ __forceinline__

typedef float f32x4 __attribute__((ext_vector_type(4)));
typedef float f4    __attribute__((ext_vector_type(4)));
typedef _Float16 h8 __attribute__((ext_vector_type(8)));
typedef _Float16 h4 __attribute__((ext_vector_type(4)));

// sizes
#define SEQL 512
#define BATCH 256
#define INF 300
#define HID 256
#define N2 512   // 2*HID
#define KP 320   // INF padded to multiple of 64

// pre3 layout: element (t, j, b) at byte t*262144 + (j>>4)*8192 + b*32 + (j&15)*2

DI float ftanh(float x) {
    float e = __builtin_amdgcn_exp2f(x * 2.8853900817779268f);
    return fmaf(-2.0f, __builtin_amdgcn_rcpf(e + 1.0f), 1.0f);
}

// ---------------- prep: WcatT (xor-swizzled f16) + bcat ----------------
__global__ void prep_kernel(const float* __restrict__ W1x, const float* __restrict__ W2x,
                            const float* __restrict__ b1, const float* __restrict__ b2,
                            _Float16* __restrict__ WTs, float* __restrict__ bcat)
{
    int idx = blockIdx.x * 256 + threadIdx.x;
    if (idx < N2 * KP) {
        int j = idx / KP, z = idx - j * KP;
        int k = z ^ ((j & 7) << 3);
        float v = 0.f;
        if (k < INF) v = (j < HID) ? W1x[k * HID + j] : W2x[k * HID + (j - HID)];
        WTs[j * KP + z] = (_Float16)v;
    }
    if (idx < N2) bcat[idx] = (idx < HID) ? b1[idx] : b2[idx - HID];
}

// ---------------- GEMM: pre3 = x @ Wcat + bcat, double-buffered (R13) ----------------
// 128m x 256j tile, 8 waves, BK=64, 2048 blocks, XCD-grouped swizzle.
// Change vs R13: LOAD_X issued before STAGE_W; mid-step wait is vmcnt(4) (x regs only),
// W-DMA keeps flying until the pre-barrier drain.
__global__ __launch_bounds__(512, 2) void gemm_pre(
    const float* __restrict__ x, const _Float16* __restrict__ WTs,
    const float* __restrict__ bcat, _Float16* __restrict__ pre3)
{
    __shared__ _Float16 AbD[2][128 * 64];  // 2 x 16KB x tile, xor-swizzled rows
    __shared__ _Float16 BbD[2][256 * 64];  // 2 x 32KB W tile, xor-swizzled rows
    const int tid = threadIdx.x;
    const int w = tid >> 6, l = tid & 63;
    const int lj = l & 15, lg = l >> 4;
    const int bid = blockIdx.x;
    const int xcd = bid & 7;
    const int idx0 = bid >> 3;
    const int jn = idx0 & 1;
    const int bm = xcd * 128 + (idx0 >> 1);
    const size_t m0 = (size_t)bm * 128;
    const int j0b = jn * 256;
    const int wj = (w >> 1) * 64, wm2 = (w & 1) * 64;

    f32x4 acc[4][4];  // [jt][mt]
#pragma unroll
    for (int a = 0; a < 4; ++a)
#pragma unroll
        for (int b = 0; b < 4; ++b) acc[a][b] = f32x4{0.f, 0.f, 0.f, 0.f};

    char* Acur = (char*)AbD[0];
    char* Anxt = (char*)AbD[1];
    char* Bcur = (char*)BbD[0];
    char* Bnxt = (char*)BbD[1];

#define STAGE_W(K0, BDST)                                                             \
    do {                                                                              \
        _Pragma("unroll")                                                             \
        for (int q = 0; q < 4; ++q) {                                                 \
            int idx = q * 512 + tid;                                                  \
            int jr = idx >> 3, sl = idx & 7;                                          \
            const _Float16* src = WTs + (size_t)(j0b + jr) * KP + (K0) + sl * 8;      \
            _Float16* dst = (_Float16*)(BDST) + (size_t)(q * 512 + w * 64) * 8;       \
            __builtin_amdgcn_global_load_lds(                                         \
                (const __attribute__((address_space(1))) void*)src,                   \
                (__attribute__((address_space(3))) void*)dst, 16, 0, 0);              \
        }                                                                             \
    } while (0)

#define LOAD_X(K0, XR)                                                                \
    do {                                                                              \
        _Pragma("unroll")                                                             \
        for (int c = 0; c < 4; ++c) {                                                 \
            int f = c * 512 + tid;                                                    \
            int mr = f >> 4, k4 = f & 15;                                             \
            if ((K0) + k4 * 4 + 3 < INF)                                              \
                XR[c] = *(const f4*)(x + (m0 + mr) * INF + (K0) + k4 * 4);            \
            else                                                                      \
                XR[c] = f4{0.f, 0.f, 0.f, 0.f};                                       \
        }                                                                             \
    } while (0)

#define WRITE_X(XR, ADST)                                                             \
    do {                                                                              \
        _Pragma("unroll")                                                             \
        for (int c = 0; c < 4; ++c) {                                                 \
            int f = c * 512 + tid;                                                    \
            int mr = f >> 4, k4 = f & 15;                                             \
            unsigned bo = (unsigned)mr * 128 + (((unsigned)k4 * 8) ^ ((mr & 7) << 4)); \
            *(h4*)((ADST) + bo) = h4{(_Float16)XR[c][0], (_Float16)XR[c][1],          \
                                     (_Float16)XR[c][2], (_Float16)XR[c][3]};         \
        }                                                                             \
    } while (0)

#define GBARRIER()                                                                    \
    do {                                                                              \
        __builtin_amdgcn_sched_barrier(0);                                            \
        asm volatile("s_waitcnt vmcnt(0) lgkmcnt(0)" ::: "memory");                   \
        __builtin_amdgcn_s_barrier();                                                 \
        __builtin_amdgcn_sched_barrier(0);                                            \
    } while (0)

    // ---- prologue: stage tile 0 ----
    {
        f4 xr[4];
        LOAD_X(0, xr);
        STAGE_W(0, Bcur);
        asm volatile("s_waitcnt vmcnt(4)" ::: "memory");  // x regs ready, W DMA flying
        WRITE_X(xr, Acur);
        GBARRIER();  // drains W DMA too
    }

    // ---- pipelined main loop ----
    for (int s = 0; s < 5; ++s) {
        f4 xr[4];
        if (s < 4) {
            const int k0n = (s + 1) * 64;
            LOAD_X(k0n, xr);      // x regs in flight (oldest)
            STAGE_W(k0n, Bnxt);   // DMA into next buffer
        }
#pragma unroll
        for (int kk = 0; kk < 2; ++kk) {
            h8 aw[4], bx[4];
#pragma unroll
            for (int jt = 0; jt < 4; ++jt) {
                int jr = wj + jt * 16 + lj;
                unsigned bo = (unsigned)jr * 128 + (((unsigned)(kk * 64 + lg * 16)) ^ ((jr & 7) << 4));
                aw[jt] = *(const h8*)(Bcur + bo);
            }
#pragma unroll
            for (int mt = 0; mt < 4; ++mt) {
                int mr = wm2 + mt * 16 + lj;
                unsigned bo = (unsigned)mr * 128 + (((unsigned)(kk * 64 + lg * 16)) ^ ((mr & 7) << 4));
                bx[mt] = *(const h8*)(Acur + bo);
            }
#pragma unroll
            for (int jt = 0; jt < 4; ++jt)
#pragma unroll
                for (int mt = 0; mt < 4; ++mt)
                    acc[jt][mt] = __builtin_amdgcn_mfma_f32_16x16x32_f16(aw[jt], bx[mt], acc[jt][mt], 0, 0, 0);
        }
        if (s < 4) {
            asm volatile("s_waitcnt vmcnt(4)" ::: "memory");  // x regs ready; W DMA flying
            WRITE_X(xr, Anxt);
        }
        GBARRIER();
        char* t0 = Acur; Acur = Anxt; Anxt = t0;
        char* t1 = Bcur; Bcur = Bnxt; Bnxt = t1;
    }
#undef STAGE_W
#undef LOAD_X
#undef WRITE_X
#undef GBARRIER

    // epilogue: bias + 16 coalesced 8B stores into pre3
    f4 bias4[4];
#pragma unroll
    for (int jt = 0; jt < 4; ++jt)
        bias4[jt] = *(const f4*)(bcat + j0b + wj + jt * 16 + lg * 4);
    char* prc = (char*)pre3;
#pragma unroll
    for (int jt = 0; jt < 4; ++jt) {
        int slab = (j0b + wj + jt * 16) >> 4;
#pragma unroll
        for (int mt = 0; mt < 4; ++mt) {
            int M = (int)m0 + wm2 + mt * 16;
            size_t byte = (size_t)(M >> 8) * 262144 + (size_t)slab * 8192
                        + (size_t)((M & 255) + lj) * 32 + (size_t)lg * 8;
            h4 o;
#pragma unroll
            for (int i = 0; i < 4; ++i)
                o[i] = (_Float16)(acc[jt][mt][i] + bias4[jt][i]);
            *(h4*)(prc + byte) = o;
        }
    }
}

// ---------------- recurrence: 32 blocks x 8 waves, explicit lgkmcnt ladder ----------------
// Per step: 8 ds_read_b128 issued in pinned order; MFMA pair kk starts at lgkmcnt(7-kk),
// so MFMAs overlap the remaining reads instead of waiting for the full cluster.
__global__ __launch_bounds__(512, 2) void rnn_scan(
    const float* __restrict__ W1h, const float* __restrict__ W2h,
    const _Float16* __restrict__ pre3, float* __restrict__ hcat)
{
    __shared__ char hbs[16384];  // [2][8192]
    char* hbc = hbs;
    const int tid = threadIdx.x;
    const int w = tid >> 6, l = tid & 63;
    const int lj = l & 15, lg = l >> 4;
    const int dir = blockIdx.x & 1;
    const int b0 = (int)(blockIdx.x >> 1) * 16;
    const float* Wh = dir ? W2h : W1h;
    const int j0 = w * 32;
    const int dirOff = dir ? HID : 0;

    h8 afrag[2][8];
#pragma unroll
    for (int jt = 0; jt < 2; ++jt) {
        int jc = j0 + jt * 16 + lj;
#pragma unroll
        for (int kk = 0; kk < 8; ++kk) {
            h8 t;
#pragma unroll
            for (int i = 0; i < 8; ++i) t[i] = (_Float16)Wh[(kk * 32 + lg * 8 + i) * HID + jc];
            afrag[jt][kk] = t;
        }
    }

    const unsigned rb = (unsigned)l * 16;
    const unsigned wb0 = (unsigned)w * 1024 + (unsigned)(lg >> 1) * 256
                       + (unsigned)lj * 16 + (unsigned)(lg & 1) * 8;

    ((h8*)hbs)[tid] = h8{0, 0, 0, 0, 0, 0, 0, 0};
    __syncthreads();

    const long long sb = dir ? -262144LL : 262144LL;
    const char* pp = (const char*)pre3 + (long long)(dir ? (SEQL - 1) : 0) * 262144
                   + (long long)dir * 131072
                   + (long long)w * 16384 + (long long)(b0 + lj) * 32 + lg * 8;
    h4 pA[2], pB[2];
#pragma unroll
    for (int jt = 0; jt < 2; ++jt) pA[jt] = *(const h4*)(pp + jt * 8192);
    pp += sb;
#pragma unroll
    for (int jt = 0; jt < 2; ++jt) pB[jt] = *(const h4*)(pp + jt * 8192);
    pp += sb;

// one pinned ds_read issue
#define RD(KK, RB)                                                                    \
        bf[KK] = *(const h8*)(hbc + (RB) + (KK) * 1024 + rb);                         \
        __builtin_amdgcn_sched_barrier(0);

// wait for read KK (7-KK still outstanding), then its MFMA pair
#define MM(KK, CNT)                                                                   \
        asm volatile("s_waitcnt lgkmcnt(" #CNT ")" ::: "memory");                     \
        __builtin_amdgcn_sched_barrier(0);                                            \
        acc0 = __builtin_amdgcn_mfma_f32_16x16x32_f16(afrag[0][KK], bf[KK], acc0, 0, 0, 0); \
        acc1 = __builtin_amdgcn_mfma_f32_16x16x32_f16(afrag[1][KK], bf[KK], acc1, 0, 0, 0);

#define RNN_STEP(RB, WB, P, DO_PF)                                                    \
    do {                                                                              \
        h8 bf[8];                                                                     \
        f32x4 acc0, acc1;                                                             \
        _Pragma("unroll")                                                             \
        for (int i = 0; i < 4; ++i) { acc0[i] = (float)P[0][i]; acc1[i] = (float)P[1][i]; } \
        __builtin_amdgcn_sched_barrier(0);                                            \
        RD(0, RB) RD(1, RB) RD(2, RB) RD(3, RB)                                       \
        RD(4, RB) RD(5, RB) RD(6, RB) RD(7, RB)                                       \
        if (DO_PF) {                                                                  \
            P[0] = *(const h4*)(pp);                                                  \
            P[1] = *(const h4*)(pp + 8192);                                           \
            pp += sb;                                                                 \
        }                                                                             \
        MM(0, 7) MM(1, 6) MM(2, 5) MM(3, 4)                                           \
        MM(4, 3) MM(5, 2) MM(6, 1) MM(7, 0)                                           \
        h4 o0, o1;                                                                    \
        _Pragma("unroll")                                                             \
        for (int i = 0; i < 4; ++i) o0[i] = (_Float16)ftanh(acc0[i]);                 \
        *(h4*)(hbc + (WB) + wb0) = o0;                                                \
        _Pragma("unroll")                                                             \
        for (int i = 0; i < 4; ++i) o1[i] = (_Float16)ftanh(acc1[i]);                 \
        *(h4*)(hbc + (WB) + wb0 + 512) = o1;                                          \
        __builtin_amdgcn_sched_barrier(0);                                            \
        asm volatile("s_waitcnt lgkmcnt(0)" ::: "memory");                            \
        __builtin_amdgcn_s_barrier();                                                 \
        __builtin_amdgcn_sched_barrier(0);                                            \
    } while (0)

    for (int tp = 0; tp < 255; ++tp) {
        RNN_STEP(0, 8192, pA, 1);
        RNN_STEP(8192, 0, pB, 1);
    }
    RNN_STEP(0, 8192, pA, 0);

    {
        // step 511: read buf1, write hcat
        f32x4 acc0, acc1;
#pragma unroll
        for (int i = 0; i < 4; ++i) { acc0[i] = (float)pB[0][i]; acc1[i] = (float)pB[1][i]; }
        h8 bf[8];
#pragma unroll
        for (int kk = 0; kk < 8; ++kk)
            bf[kk] = *(const h8*)(hbc + 8192 + kk * 1024 + rb);
#pragma unroll
        for (int kk = 0; kk < 8; ++kk) {
            acc0 = __builtin_amdgcn_mfma_f32_16x16x32_f16(afrag[0][kk], bf[kk], acc0, 0, 0, 0);
            acc1 = __builtin_amdgcn_mfma_f32_16x16x32_f16(afrag[1][kk], bf[kk], acc1, 0, 0, 0);
        }
        f4 v0, v1;
#pragma unroll
        for (int i = 0; i < 4; ++i) { v0[i] = ftanh(acc0[i]); v1[i] = ftanh(acc1[i]); }
        float* hc = hcat + (size_t)(b0 + lj) * N2 + dirOff + j0 + lg * 4;
        *(f4*)hc = v0;
        *(f4*)(hc + 16) = v1;
    }
#undef RNN_STEP
#undef MM
#undef RD
}

// ---------------- head: 64 blocks x 4 batch-rows (R6-verified) ----------------
__global__ __launch_bounds__(256) void head_mlp(
    const float* __restrict__ hcat,
    const float* __restrict__ fc1w, const float* __restrict__ fc1b,
    const float* __restrict__ fc2w, const float* __restrict__ fc2b,
    const float* __restrict__ fsw, const float* __restrict__ fsb,
    float* __restrict__ out)
{
    __shared__ float hs[4 * 512];
    __shared__ float y1[4 * 512];
    __shared__ float y2[4 * 256];
    const int tid = threadIdx.x;
    const int b0 = blockIdx.x * 4;
    const int r = tid >> 6;
    const int lane = tid & 63;

#pragma unroll
    for (int c = 0; c < 2; ++c)
        ((f4*)hs)[c * 256 + tid] = ((const f4*)(hcat + (size_t)b0 * N2))[c * 256 + tid];
    __syncthreads();

    {
        const int j0 = lane * 8;
        f4 a0 = *(const f4*)(fc1b + j0);
        f4 a1 = *(const f4*)(fc1b + j0 + 4);
        for (int k = 0; k < 512; ++k) {
            float h = hs[r * 512 + k];
            f4 w0 = *(const f4*)(fc1w + (size_t)k * 512 + j0);
            f4 w1 = *(const f4*)(fc1w + (size_t)k * 512 + j0 + 4);
#pragma unroll
            for (int i = 0; i < 4; ++i) { a0[i] = fmaf(h, w0[i], a0[i]); a1[i] = fmaf(h, w1[i], a1[i]); }
        }
#pragma unroll
        for (int i = 0; i < 4; ++i) {
            y1[r * 512 + j0 + i]     = fmaxf(a0[i], 0.f);
            y1[r * 512 + j0 + 4 + i] = fmaxf(a1[i], 0.f);
        }
    }
    __syncthreads();

    {
        const int j2 = lane * 4;
        f4 a = *(const f4*)(fc2b + j2);
        for (int k = 0; k < 512; ++k) {
            float yv = y1[r * 512 + k];
            f4 w = *(const f4*)(fc2w + (size_t)k * 256 + j2);
#pragma unroll
            for (int i = 0; i < 4; ++i) a[i] = fmaf(yv, w[i], a[i]);
        }
#pragma unroll
        for (int i = 0; i < 4; ++i) y2[r * 256 + j2 + i] = fmaxf(a[i], 0.f);
    }
    __syncthreads();

    {
        float p = 0.f;
#pragma unroll
        for (int u = 0; u < 4; ++u)
            p = fmaf(y2[r * 256 + lane + u * 64], fsw[lane + u * 64], p);
#pragma unroll
        for (int off = 32; off > 0; off >>= 1) p += __shfl_down(p, off);
        if (lane == 0) out[b0 + r] = ftanh(p + fsb[0]);
    }
}

extern "C" void kernel_launch(void* const* d_in, const int* in_sizes, int n_in,
                              void* d_out, int out_size, void* d_ws, size_t ws_size,
                              hipStream_t stream)
{
    const float* x    = (const float*)d_in[0];
    const float* W1x  = (const float*)d_in[1];
    const float* W1h  = (const float*)d_in[2];
    const float* b1   = (const float*)d_in[3];
    const float* W2x  = (const float*)d_in[4];
    const float* W2h  = (const float*)d_in[5];
    const float* b2   = (const float*)d_in[6];
    const float* fc1w = (const float*)d_in[7];
    const float* fc1b = (const float*)d_in[8];
    const float* fc2w = (const float*)d_in[9];
    const float* fc2b = (const float*)d_in[10];
    const float* fsw  = (const float*)d_in[11];
    const float* fsb  = (const float*)d_in[12];

    char* ws = (char*)d_ws;
    size_t off = 0;
    _Float16* WTs  = (_Float16*)(ws + off); off += (size_t)N2 * KP * sizeof(_Float16);
    float* bcat    = (float*)(ws + off);    off += (size_t)N2 * sizeof(float);
    float* hcat    = (float*)(ws + off);    off += (size_t)BATCH * N2 * sizeof(float);
    _Float16* pre3 = (_Float16*)(ws + off); off += (size_t)SEQL * BATCH * N2 * sizeof(_Float16);
    if (off > ws_size) return;

    prep_kernel<<<(N2 * KP + 255) / 256, 256, 0, stream>>>(W1x, W2x, b1, b2, WTs, bcat);
    gemm_pre<<<2048, 512, 0, stream>>>(x, WTs, bcat, pre3);
    rnn_scan<<<(BATCH / 16) * 2, 512, 0, stream>>>(W1h, W2h, pre3, hcat);
    head_mlp<<<64, 256, 0, stream>>>(hcat, fc1w, fc1b, fc2w, fc2b, fsw, fsb, (float*)d_out);
}